// Round 3
// baseline (431.503 us; speedup 1.0000x reference)
//
#include <hip/hip_runtime.h>
#include <hip/hip_bf16.h>
#include <cstdint>

// B=8, N=1024, T=32, F=64.  256 independent attention problems of (N=1024, F=64).
// out = relu( ((adj ⊙ softmax(X Xᵀ/8)) X / 8) θᵀ ) per (b,t); X row n = x[b,n,t,:].
// fp32 I/O. Round-8: keep round-6's verified structural wins (dual-write Xkh/Xv
// stager kills the Xv-build phase; SC folded into Q frags + diag norm) but revert
// the two unverified mechanisms that broke rounds 6-7: P-exchange back to the
// known-good shufB cross-lane path (no same-wave LDS write->read without waitcnt),
// and exp via __builtin_amdgcn_exp2f (compiler-visible v_exp_f32, hazard-safe)
// instead of an opaque inline-asm blob.
// LDS = 16 KB (Xkh 8K + Xv 8K); 4 blocks/CU (thread-cap bound).
#define NN 1024
#define ROWSTRIDE 2048   // NT*NF

typedef __attribute__((ext_vector_type(8))) short bf16x8;
typedef __attribute__((ext_vector_type(4))) float f32x4;
typedef unsigned short u16;

#if __has_builtin(__builtin_amdgcn_exp2f)
#define EXP2(x) __builtin_amdgcn_exp2f(x)
#else
#define EXP2(x) exp2f(x)
#endif

__device__ __forceinline__ f32x4 mfma_bf16(bf16x8 a, bf16x8 b, f32x4 c) {
    return __builtin_amdgcn_mfma_f32_16x16x32_bf16(a, b, c, 0, 0, 0);
}
__device__ __forceinline__ float bf16_to_f32(u16 h) {
    unsigned int u = ((unsigned int)h) << 16;
    return __builtin_bit_cast(float, u);
}
__device__ __forceinline__ u16 f32_to_bf16(float f) {
    __hip_bfloat16 h = __float2bfloat16(f);   // RNE
    return __builtin_bit_cast(u16, h);
}
__device__ __forceinline__ uint32_t pack2(float a, float b) {
    return (uint32_t)f32_to_bf16(a) | ((uint32_t)f32_to_bf16(b) << 16);
}
__device__ __forceinline__ void ldadj4(const u16* p, int i, float* o) {
    ushort4 v = *(const ushort4*)(p + i);
    o[0] = bf16_to_f32(v.x); o[1] = bf16_to_f32(v.y);
    o[2] = bf16_to_f32(v.z); o[3] = bf16_to_f32(v.w);
}
__device__ __forceinline__ void ldadj4(const float* p, int i, float* o) {
    float4 v = *(const float4*)(p + i);
    o[0] = v.x; o[1] = v.y; o[2] = v.z; o[3] = v.w;
}

__global__ void cvt_adj_kernel(const float* __restrict__ a, u16* __restrict__ o) {
    int i = (blockIdx.x * 256 + threadIdx.x) * 4;
    float4 v = *(const float4*)(a + i);
    ushort4 h;
    h.x = f32_to_bf16(v.x); h.y = f32_to_bf16(v.y);
    h.z = f32_to_bf16(v.z); h.w = f32_to_bf16(v.w);
    *(ushort4*)(o + i) = h;
}

// MFMA 16x16x32 layouts (HW-verified):
//   A: A[m=lane&15][k=(lane>>4)*8+r]   B: B[k=(lane>>4)*8+r][n=lane&15]
//   C/D: D[row=(lane>>4)*4+reg][col=lane&15]
//
// C/D -> B-frag transform (keys axis): lane(l16,q') B-frag u32 j of chunk kc comes from
// pk[t=2kc+(q'>>1)] of lane l16+16*(2(q'&1) + (j>>1)), pair d(j&1).
__device__ __forceinline__ bf16x8 shufB(const uint32_t* d0, const uint32_t* d1,
                                        int kc, int srcA, int srcB, bool qhi) {
    uint32_t l0A = (uint32_t)__shfl((int)d0[2*kc],     srcA);
    uint32_t l1A = (uint32_t)__shfl((int)d1[2*kc],     srcA);
    uint32_t l0B = (uint32_t)__shfl((int)d0[2*kc],     srcB);
    uint32_t l1B = (uint32_t)__shfl((int)d1[2*kc],     srcB);
    uint32_t h0A = (uint32_t)__shfl((int)d0[2*kc + 1], srcA);
    uint32_t h1A = (uint32_t)__shfl((int)d1[2*kc + 1], srcA);
    uint32_t h0B = (uint32_t)__shfl((int)d0[2*kc + 1], srcB);
    uint32_t h1B = (uint32_t)__shfl((int)d1[2*kc + 1], srcB);
    union { uint32_t u[4]; bf16x8 v; } R;
    R.u[0] = qhi ? h0A : l0A;
    R.u[1] = qhi ? h1A : l1A;
    R.u[2] = qhi ? h0B : l0B;
    R.u[3] = qhi ? h1B : l1B;
    return R.v;
}

template <typename AT>
__launch_bounds__(512, 4)
__global__ void attn_gcn_kernel(const float* __restrict__ x,
                                const AT*   __restrict__ adj,
                                const float* __restrict__ theta,
                                float* __restrict__ out)
{
    // Xkh: 64 keys x 64 f, 16B-chunk swizzle: phys chunk = fc ^ (key&7)
    // Xv:  64 f x 64 keys (transposed), phys chunk = mc ^ (f&7) ^ (f>>3)
    //      (the ^(f>>3) term spreads the stager's scalar scatter writes: the
    //      dual-write puts the whole wave's 8x8 u16 scatter at 2 lanes/bank)
    __shared__ __align__(16) u16 Xkh [64 * 64];        // 8192 B
    __shared__ __align__(16) u16 Xv  [64 * 64];        // 8192 B   (total 16 KB)

    const int tid  = threadIdx.x;
    const int lane = tid & 63;
    const int wid  = tid >> 6;
    const int l16  = lane & 15;
    const int q    = lane >> 4;
    const bool qhi = (q >> 1) != 0;
    const int srcA = l16 + 32 * (q & 1);
    const int srcB = srcA + 16;

    const int blk = blockIdx.x;
    const int p   = blk & 255;        // problem (b*32+t); qb-major for adj L2 reuse
    const int qb  = blk >> 8;
    const int b   = p >> 5;
    const int t   = p & 31;

    const float* xb = x + (size_t)b * NN * ROWSTRIDE + (size_t)t * 64;
    const int    i0 = qb * 256 + wid * 32;   // wave's 32 query rows

    const float SC = 0.125f * 1.44269504088896340736f;   // exp(S/8)=exp2(S*SC)

    // ---- Q B-frags (pre-scaled by SC) + exact row norms (fp32, scaled)
    bf16x8 bq[2][2];
    float  nrm[2] = {0.f, 0.f};
#pragma unroll
    for (int s = 0; s < 2; ++s) {
#pragma unroll
        for (int kc = 0; kc < 2; ++kc) {
            const float* qp = xb + (size_t)(i0 + s * 16 + l16) * ROWSTRIDE + kc * 32 + q * 8;
            float4 v0 = *(const float4*)qp;
            float4 v1 = *(const float4*)(qp + 4);
            float vv[8] = {v0.x, v0.y, v0.z, v0.w, v1.x, v1.y, v1.z, v1.w};
            union { u16 h[8]; bf16x8 v; } H;
#pragma unroll
            for (int r = 0; r < 8; ++r) {
                nrm[s] += vv[r] * vv[r];
                H.h[r] = f32_to_bf16(vv[r] * SC);
            }
            bq[s][kc] = H.v;
        }
        nrm[s] += __shfl_xor(nrm[s], 16);
        nrm[s] += __shfl_xor(nrm[s], 32);
        nrm[s] *= SC;      // diag substitution directly in exp2 domain
    }
    // diagonal location: key n lands in k-tile kbd[s], sub-tile ktd[s],
    // C/D lane q == l16>>2, element r == l16&3   (i0+16s is a multiple of 16)
    const int kbd0 = (i0) >> 6,        ktd0 = ((i0) >> 4) & 3;
    const int kbd1 = (i0 + 16) >> 6,   ktd1 = ((i0 + 16) >> 4) & 3;
    const bool dlane = (q == (l16 >> 2));
    const int  dr    = l16 & 3;

    // per-lane adj row base (n = i0 + 16s + l16)
    const AT* adjr0 = adj + (size_t)(i0 + l16) * NN;
    const AT* adjr1 = adj + (size_t)(i0 + 16 + l16) * NN;

    const f32x4 zero4 = {0.f, 0.f, 0.f, 0.f};
    f32x4 acc[2][4];
#pragma unroll
    for (int s = 0; s < 2; ++s)
#pragma unroll
        for (int ft = 0; ft < 4; ++ft) acc[s][ft] = zero4;
    float dp[2] = {0.f, 0.f};

    // staging role: key row js, f-chunk fcs (8 floats)
    const int js = tid >> 3, fcs = tid & 7;
    const int wxf = (js >> 3) ^ fcs;                 // Xv scatter swizzle base
    const float* gbase = xb + (size_t)js * ROWSTRIDE + fcs * 8;
    float4 g0 = *(const float4*)gbase;               // prefetch kb=0
    float4 g1 = *(const float4*)(gbase + 4);

#pragma unroll 1
    for (int kb = 0; kb < 16; ++kb) {
        const int j0 = kb * 64;

        // ---- stage X-tile: dual-write row-major Xkh (b128) + transposed Xv (8x b16)
        {
            float vv[8] = {g0.x, g0.y, g0.z, g0.w, g1.x, g1.y, g1.z, g1.w};
            union { u16 h[8]; uint4 u; } H;
#pragma unroll
            for (int r = 0; r < 8; ++r) H.h[r] = f32_to_bf16(vv[r]);
            *(uint4*)&Xkh[js * 64 + ((fcs ^ (js & 7)) << 3)] = H.u;
            // Xv[f=fcs*8+r][key=js], phys chunk = (js>>3) ^ (f&7) ^ (f>>3)
#pragma unroll
            for (int r = 0; r < 8; ++r)
                Xv[(fcs * 8 + r) * 64 + ((wxf ^ r) << 3) + (js & 7)] = H.h[r];
        }
        __syncthreads();   // A: both layouts staged (prev-iter reads done at barrier B)

        // ---- Sᵀ = K·Qᵀ (bf16) -> exact-diag fix -> exp -> ×adj -> packed P in regs
        uint32_t pk0[2][4], pk1[2][4];   // [s][kt]: keys 16kt+4q+{0,1} / {2,3}
#pragma unroll
        for (int kt = 0; kt < 4; ++kt) {
            const int base = (kt * 16 + l16) * 64;   // (kt*16+l16)&7 == l16&7
            const int sw   = l16 & 7;
            bf16x8 akh0 = *(const bf16x8*)&Xkh[base + ((q ^ sw) << 3)];
            bf16x8 akh1 = *(const bf16x8*)&Xkh[base + (((4 + q) ^ sw) << 3)];
#pragma unroll
            for (int s = 0; s < 2; ++s) {
                f32x4 z = zero4;
                z = mfma_bf16(akh0, bq[s][0], z);
                z = mfma_bf16(akh1, bq[s][1], z);
                // exact diagonal substitution (already in exp2 domain)
                const bool isd = (s == 0) ? (kb == kbd0 && kt == ktd0)
                                          : (kb == kbd1 && kt == ktd1);
                if (isd && dlane) {
#pragma unroll
                    for (int r = 0; r < 4; ++r)
                        if (r == dr) z[r] = nrm[s];
                }
                float av[4];
                ldadj4((s == 0) ? adjr0 : adjr1, j0 + kt * 16 + q * 4, av);
                float e0 = EXP2(z[0]), e1 = EXP2(z[1]);
                float e2 = EXP2(z[2]), e3 = EXP2(z[3]);
                dp[s] += (e0 + e1) + (e2 + e3);
                pk0[s][kt] = pack2(e0 * av[0], e1 * av[1]);
                pk1[s][kt] = pack2(e2 * av[2], e3 * av[3]);
            }
        }

        // ---- prefetch next X-tile into regs (overlaps P-shuffle + PV MFMAs)
        if (kb < 15) {
            const float* gp = gbase + (size_t)(j0 + 64) * ROWSTRIDE;
            g0 = *(const float4*)gp;
            g1 = *(const float4*)(gp + 4);
        }

        // ---- PV: aggᵀ[f][n] += Xv(A) · Pᵀ(B);  Pᵀ B-frags via cross-lane shuffles
#pragma unroll
        for (int kc = 0; kc < 2; ++kc) {
            bf16x8 bp0 = shufB(pk0[0], pk1[0], kc, srcA, srcB, qhi);
            bf16x8 bp1 = shufB(pk0[1], pk1[1], kc, srcA, srcB, qhi);
#pragma unroll
            for (int ft = 0; ft < 4; ++ft) {
                const int fr  = ft * 16 + l16;
                const int swz = (kc * 4 + q) ^ (l16 & 7) ^ ((ft << 1) | (l16 >> 3));
                bf16x8 axv = *(const bf16x8*)&Xv[fr * 64 + (swz << 3)];
                acc[0][ft] = mfma_bf16(axv, bp0, acc[0][ft]);
                acc[1][ft] = mfma_bf16(axv, bp1, acc[1][ft]);
            }
        }
        __syncthreads();   // B: all Xkh/Xv reads done -> next stage may overwrite
    }

    // ---- denominator reduce: lanes {l16 + 16q} share n
    float inv8d[2];
#pragma unroll
    for (int s = 0; s < 2; ++s) {
        float v = dp[s];
        v += __shfl_xor(v, 16);
        v += __shfl_xor(v, 32);
        inv8d[s] = 1.0f / (8.0f * v);   // extra 1/sqrt(F) from GCN forward
    }

    // ---- epilogue: outᵀ = θ(A) · aggᵀ(B); agg C/D -> B-frag via shufB (once)
    bf16x8 th[4][2];   // A[m=l16 (fo in tile fot)][k=kc2*32+q*8+r] = θ[fot*16+l16][...]
#pragma unroll
    for (int fot = 0; fot < 4; ++fot)
#pragma unroll
        for (int kc = 0; kc < 2; ++kc) {
            const float* tp = theta + (fot * 16 + l16) * 64 + kc * 32 + q * 8;
            float4 v0 = *(const float4*)tp;
            float4 v1 = *(const float4*)(tp + 4);
            float vv[8] = {v0.x, v0.y, v0.z, v0.w, v1.x, v1.y, v1.z, v1.w};
            union { u16 h[8]; bf16x8 v; } H;
#pragma unroll
            for (int r = 0; r < 8; ++r) H.h[r] = f32_to_bf16(vv[r]);
            th[fot][kc] = H.v;
        }

    float* ob = out + (size_t)b * NN * ROWSTRIDE + (size_t)t * 64;
#pragma unroll
    for (int s = 0; s < 2; ++s) {
        uint32_t ed0[4], ed1[4];   // packed agg/(8d): f = 16ft+4q+{0,1}/{2,3}
#pragma unroll
        for (int ft = 0; ft < 4; ++ft) {
            ed0[ft] = pack2(acc[s][ft][0] * inv8d[s], acc[s][ft][1] * inv8d[s]);
            ed1[ft] = pack2(acc[s][ft][2] * inv8d[s], acc[s][ft][3] * inv8d[s]);
        }
        const int n = i0 + s * 16 + l16;
#pragma unroll
        for (int kc = 0; kc < 2; ++kc) {
            bf16x8 bg = shufB(ed0, ed1, kc, srcA, srcB, qhi);
            if (kc == 0) {
#pragma unroll
                for (int fot = 0; fot < 4; ++fot) {
                    f32x4 z = zero4;
                    z = mfma_bf16(th[fot][0], bg, z);
                    acc[s][fot] = z;   // stash partial (acc no longer needed)
                }
            } else {
#pragma unroll
                for (int fot = 0; fot < 4; ++fot) {
                    f32x4 z = mfma_bf16(th[fot][1], bg, acc[s][fot]);
                    float4 o4;
                    o4.x = z[0] > 0.f ? z[0] : 0.f;
                    o4.y = z[1] > 0.f ? z[1] : 0.f;
                    o4.z = z[2] > 0.f ? z[2] : 0.f;
                    o4.w = z[3] > 0.f ? z[3] : 0.f;
                    *(float4*)(ob + (size_t)n * ROWSTRIDE + fot * 16 + q * 4) = o4;
                }
            }
        }
    }
}

extern "C" void kernel_launch(void* const* d_in, const int* in_sizes, int n_in,
                              void* d_out, int out_size, void* d_ws, size_t ws_size,
                              hipStream_t stream) {
    const float* x     = (const float*)d_in[0];   // (8,1024,32,64) fp32
    const float* adj   = (const float*)d_in[1];   // (1024,1024)   fp32
    const float* theta = (const float*)d_in[2];   // (64,64)       fp32
    float* o = (float*)d_out;                     // (8,1024,32,64) fp32

    const size_t adj_bytes = (size_t)NN * NN * sizeof(u16);
    if (ws_size >= adj_bytes) {
        u16* adjb = (u16*)d_ws;
        cvt_adj_kernel<<<dim3(NN * NN / (256 * 4)), dim3(256), 0, stream>>>(adj, adjb);
        attn_gcn_kernel<u16><<<dim3(1024), dim3(512), 0, stream>>>(x, adjb, theta, o);
    } else {
        attn_gcn_kernel<float><<<dim3(1024), dim3(512), 0, stream>>>(x, adj, theta, o);
    }
}

// Round 4
// 330.127 us; speedup vs baseline: 1.3071x; 1.3071x over previous
//
#include <hip/hip_runtime.h>
#include <hip/hip_bf16.h>
#include <cstdint>

// B=8, N=1024, T=32, F=64.  256 independent attention problems of (N=1024, F=64).
// out = relu( ((adj ⊙ softmax(X Xᵀ/8)) X / 8) θᵀ ) per (b,t); X row n = x[b,n,t,:].
// fp32 I/O. Round-9: round-8 structure unchanged (dual-write Xkh/Xv stager, shufB
// P-exchange, builtin exp2, SC folded into Q) + THE fix: __launch_bounds__(512,4)
// was capping the allocator at 64 VGPRs (observed VGPR_Count=64 every round) while
// the main loop keeps ~100 values live -> per-iteration scratch spills. Evidence:
// WRITE_SIZE 106-145 MB vs 67 MB output, FETCH_SIZE 190-415 MB vs ~90 MB unique
// inputs, and a regression whenever codegen changed spill victims. (512,2) raises
// the cap to 128 VGPRs: spill-free at ~16 waves/CU (measured occupancy was only
// ~42% anyway, so the 8-wave/SIMD residency the 64-cap bought was never realized).
// LDS = 16 KB (Xkh 8K + Xv 8K).
#define NN 1024
#define ROWSTRIDE 2048   // NT*NF

typedef __attribute__((ext_vector_type(8))) short bf16x8;
typedef __attribute__((ext_vector_type(4))) float f32x4;
typedef unsigned short u16;

#if __has_builtin(__builtin_amdgcn_exp2f)
#define EXP2(x) __builtin_amdgcn_exp2f(x)
#else
#define EXP2(x) exp2f(x)
#endif

__device__ __forceinline__ f32x4 mfma_bf16(bf16x8 a, bf16x8 b, f32x4 c) {
    return __builtin_amdgcn_mfma_f32_16x16x32_bf16(a, b, c, 0, 0, 0);
}
__device__ __forceinline__ float bf16_to_f32(u16 h) {
    unsigned int u = ((unsigned int)h) << 16;
    return __builtin_bit_cast(float, u);
}
__device__ __forceinline__ u16 f32_to_bf16(float f) {
    __hip_bfloat16 h = __float2bfloat16(f);   // RNE
    return __builtin_bit_cast(u16, h);
}
__device__ __forceinline__ uint32_t pack2(float a, float b) {
    return (uint32_t)f32_to_bf16(a) | ((uint32_t)f32_to_bf16(b) << 16);
}
__device__ __forceinline__ void ldadj4(const u16* p, int i, float* o) {
    ushort4 v = *(const ushort4*)(p + i);
    o[0] = bf16_to_f32(v.x); o[1] = bf16_to_f32(v.y);
    o[2] = bf16_to_f32(v.z); o[3] = bf16_to_f32(v.w);
}
__device__ __forceinline__ void ldadj4(const float* p, int i, float* o) {
    float4 v = *(const float4*)(p + i);
    o[0] = v.x; o[1] = v.y; o[2] = v.z; o[3] = v.w;
}

__global__ void cvt_adj_kernel(const float* __restrict__ a, u16* __restrict__ o) {
    int i = (blockIdx.x * 256 + threadIdx.x) * 4;
    float4 v = *(const float4*)(a + i);
    ushort4 h;
    h.x = f32_to_bf16(v.x); h.y = f32_to_bf16(v.y);
    h.z = f32_to_bf16(v.z); h.w = f32_to_bf16(v.w);
    *(ushort4*)(o + i) = h;
}

// MFMA 16x16x32 layouts (HW-verified):
//   A: A[m=lane&15][k=(lane>>4)*8+r]   B: B[k=(lane>>4)*8+r][n=lane&15]
//   C/D: D[row=(lane>>4)*4+reg][col=lane&15]
//
// C/D -> B-frag transform (keys axis): lane(l16,q') B-frag u32 j of chunk kc comes from
// pk[t=2kc+(q'>>1)] of lane l16+16*(2(q'&1) + (j>>1)), pair d(j&1).
__device__ __forceinline__ bf16x8 shufB(const uint32_t* d0, const uint32_t* d1,
                                        int kc, int srcA, int srcB, bool qhi) {
    uint32_t l0A = (uint32_t)__shfl((int)d0[2*kc],     srcA);
    uint32_t l1A = (uint32_t)__shfl((int)d1[2*kc],     srcA);
    uint32_t l0B = (uint32_t)__shfl((int)d0[2*kc],     srcB);
    uint32_t l1B = (uint32_t)__shfl((int)d1[2*kc],     srcB);
    uint32_t h0A = (uint32_t)__shfl((int)d0[2*kc + 1], srcA);
    uint32_t h1A = (uint32_t)__shfl((int)d1[2*kc + 1], srcA);
    uint32_t h0B = (uint32_t)__shfl((int)d0[2*kc + 1], srcB);
    uint32_t h1B = (uint32_t)__shfl((int)d1[2*kc + 1], srcB);
    union { uint32_t u[4]; bf16x8 v; } R;
    R.u[0] = qhi ? h0A : l0A;
    R.u[1] = qhi ? h1A : l1A;
    R.u[2] = qhi ? h0B : l0B;
    R.u[3] = qhi ? h1B : l1B;
    return R.v;
}

template <typename AT>
__launch_bounds__(512, 2)
__global__ void attn_gcn_kernel(const float* __restrict__ x,
                                const AT*   __restrict__ adj,
                                const float* __restrict__ theta,
                                float* __restrict__ out)
{
    // Xkh: 64 keys x 64 f, 16B-chunk swizzle: phys chunk = fc ^ (key&7)
    // Xv:  64 f x 64 keys (transposed), phys chunk = mc ^ (f&7) ^ (f>>3)
    //      (the ^(f>>3) term spreads the stager's scalar scatter writes: the
    //      dual-write puts the whole wave's 8x8 u16 scatter at 2 lanes/bank)
    __shared__ __align__(16) u16 Xkh [64 * 64];        // 8192 B
    __shared__ __align__(16) u16 Xv  [64 * 64];        // 8192 B   (total 16 KB)

    const int tid  = threadIdx.x;
    const int lane = tid & 63;
    const int wid  = tid >> 6;
    const int l16  = lane & 15;
    const int q    = lane >> 4;
    const bool qhi = (q >> 1) != 0;
    const int srcA = l16 + 32 * (q & 1);
    const int srcB = srcA + 16;

    const int blk = blockIdx.x;
    const int p   = blk & 255;        // problem (b*32+t); qb-major for adj L2 reuse
    const int qb  = blk >> 8;
    const int b   = p >> 5;
    const int t   = p & 31;

    const float* xb = x + (size_t)b * NN * ROWSTRIDE + (size_t)t * 64;
    const int    i0 = qb * 256 + wid * 32;   // wave's 32 query rows

    const float SC = 0.125f * 1.44269504088896340736f;   // exp(S/8)=exp2(S*SC)

    // ---- Q B-frags (pre-scaled by SC) + exact row norms (fp32, scaled)
    bf16x8 bq[2][2];
    float  nrm[2] = {0.f, 0.f};
#pragma unroll
    for (int s = 0; s < 2; ++s) {
#pragma unroll
        for (int kc = 0; kc < 2; ++kc) {
            const float* qp = xb + (size_t)(i0 + s * 16 + l16) * ROWSTRIDE + kc * 32 + q * 8;
            float4 v0 = *(const float4*)qp;
            float4 v1 = *(const float4*)(qp + 4);
            float vv[8] = {v0.x, v0.y, v0.z, v0.w, v1.x, v1.y, v1.z, v1.w};
            union { u16 h[8]; bf16x8 v; } H;
#pragma unroll
            for (int r = 0; r < 8; ++r) {
                nrm[s] += vv[r] * vv[r];
                H.h[r] = f32_to_bf16(vv[r] * SC);
            }
            bq[s][kc] = H.v;
        }
        nrm[s] += __shfl_xor(nrm[s], 16);
        nrm[s] += __shfl_xor(nrm[s], 32);
        nrm[s] *= SC;      // diag substitution directly in exp2 domain
    }
    // diagonal location: key n lands in k-tile kbd[s], sub-tile ktd[s],
    // C/D lane q == l16>>2, element r == l16&3   (i0+16s is a multiple of 16)
    const int kbd0 = (i0) >> 6,        ktd0 = ((i0) >> 4) & 3;
    const int kbd1 = (i0 + 16) >> 6,   ktd1 = ((i0 + 16) >> 4) & 3;
    const bool dlane = (q == (l16 >> 2));
    const int  dr    = l16 & 3;

    // per-lane adj row base (n = i0 + 16s + l16)
    const AT* adjr0 = adj + (size_t)(i0 + l16) * NN;
    const AT* adjr1 = adj + (size_t)(i0 + 16 + l16) * NN;

    const f32x4 zero4 = {0.f, 0.f, 0.f, 0.f};
    f32x4 acc[2][4];
#pragma unroll
    for (int s = 0; s < 2; ++s)
#pragma unroll
        for (int ft = 0; ft < 4; ++ft) acc[s][ft] = zero4;
    float dp[2] = {0.f, 0.f};

    // staging role: key row js, f-chunk fcs (8 floats)
    const int js = tid >> 3, fcs = tid & 7;
    const int wxf = (js >> 3) ^ fcs;                 // Xv scatter swizzle base
    const float* gbase = xb + (size_t)js * ROWSTRIDE + fcs * 8;
    float4 g0 = *(const float4*)gbase;               // prefetch kb=0
    float4 g1 = *(const float4*)(gbase + 4);

#pragma unroll 1
    for (int kb = 0; kb < 16; ++kb) {
        const int j0 = kb * 64;

        // ---- stage X-tile: dual-write row-major Xkh (b128) + transposed Xv (8x b16)
        {
            float vv[8] = {g0.x, g0.y, g0.z, g0.w, g1.x, g1.y, g1.z, g1.w};
            union { u16 h[8]; uint4 u; } H;
#pragma unroll
            for (int r = 0; r < 8; ++r) H.h[r] = f32_to_bf16(vv[r]);
            *(uint4*)&Xkh[js * 64 + ((fcs ^ (js & 7)) << 3)] = H.u;
            // Xv[f=fcs*8+r][key=js], phys chunk = (js>>3) ^ (f&7) ^ (f>>3)
#pragma unroll
            for (int r = 0; r < 8; ++r)
                Xv[(fcs * 8 + r) * 64 + ((wxf ^ r) << 3) + (js & 7)] = H.h[r];
        }
        __syncthreads();   // A: both layouts staged (prev-iter reads done at barrier B)

        // ---- Sᵀ = K·Qᵀ (bf16) -> exact-diag fix -> exp -> ×adj -> packed P in regs
        uint32_t pk0[2][4], pk1[2][4];   // [s][kt]: keys 16kt+4q+{0,1} / {2,3}
#pragma unroll
        for (int kt = 0; kt < 4; ++kt) {
            const int base = (kt * 16 + l16) * 64;   // (kt*16+l16)&7 == l16&7
            const int sw   = l16 & 7;
            bf16x8 akh0 = *(const bf16x8*)&Xkh[base + ((q ^ sw) << 3)];
            bf16x8 akh1 = *(const bf16x8*)&Xkh[base + (((4 + q) ^ sw) << 3)];
#pragma unroll
            for (int s = 0; s < 2; ++s) {
                f32x4 z = zero4;
                z = mfma_bf16(akh0, bq[s][0], z);
                z = mfma_bf16(akh1, bq[s][1], z);
                // exact diagonal substitution (already in exp2 domain)
                const bool isd = (s == 0) ? (kb == kbd0 && kt == ktd0)
                                          : (kb == kbd1 && kt == ktd1);
                if (isd && dlane) {
#pragma unroll
                    for (int r = 0; r < 4; ++r)
                        if (r == dr) z[r] = nrm[s];
                }
                float av[4];
                ldadj4((s == 0) ? adjr0 : adjr1, j0 + kt * 16 + q * 4, av);
                float e0 = EXP2(z[0]), e1 = EXP2(z[1]);
                float e2 = EXP2(z[2]), e3 = EXP2(z[3]);
                dp[s] += (e0 + e1) + (e2 + e3);
                pk0[s][kt] = pack2(e0 * av[0], e1 * av[1]);
                pk1[s][kt] = pack2(e2 * av[2], e3 * av[3]);
            }
        }

        // ---- prefetch next X-tile into regs (overlaps P-shuffle + PV MFMAs)
        if (kb < 15) {
            const float* gp = gbase + (size_t)(j0 + 64) * ROWSTRIDE;
            g0 = *(const float4*)gp;
            g1 = *(const float4*)(gp + 4);
        }

        // ---- PV: aggᵀ[f][n] += Xv(A) · Pᵀ(B);  Pᵀ B-frags via cross-lane shuffles
#pragma unroll
        for (int kc = 0; kc < 2; ++kc) {
            bf16x8 bp0 = shufB(pk0[0], pk1[0], kc, srcA, srcB, qhi);
            bf16x8 bp1 = shufB(pk0[1], pk1[1], kc, srcA, srcB, qhi);
#pragma unroll
            for (int ft = 0; ft < 4; ++ft) {
                const int fr  = ft * 16 + l16;
                const int swz = (kc * 4 + q) ^ (l16 & 7) ^ ((ft << 1) | (l16 >> 3));
                bf16x8 axv = *(const bf16x8*)&Xv[fr * 64 + (swz << 3)];
                acc[0][ft] = mfma_bf16(axv, bp0, acc[0][ft]);
                acc[1][ft] = mfma_bf16(axv, bp1, acc[1][ft]);
            }
        }
        __syncthreads();   // B: all Xkh/Xv reads done -> next stage may overwrite
    }

    // ---- denominator reduce: lanes {l16 + 16q} share n
    float inv8d[2];
#pragma unroll
    for (int s = 0; s < 2; ++s) {
        float v = dp[s];
        v += __shfl_xor(v, 16);
        v += __shfl_xor(v, 32);
        inv8d[s] = 1.0f / (8.0f * v);   // extra 1/sqrt(F) from GCN forward
    }

    // ---- epilogue: outᵀ = θ(A) · aggᵀ(B); agg C/D -> B-frag via shufB (once)
    bf16x8 th[4][2];   // A[m=l16 (fo in tile fot)][k=kc2*32+q*8+r] = θ[fot*16+l16][...]
#pragma unroll
    for (int fot = 0; fot < 4; ++fot)
#pragma unroll
        for (int kc = 0; kc < 2; ++kc) {
            const float* tp = theta + (fot * 16 + l16) * 64 + kc * 32 + q * 8;
            float4 v0 = *(const float4*)tp;
            float4 v1 = *(const float4*)(tp + 4);
            float vv[8] = {v0.x, v0.y, v0.z, v0.w, v1.x, v1.y, v1.z, v1.w};
            union { u16 h[8]; bf16x8 v; } H;
#pragma unroll
            for (int r = 0; r < 8; ++r) H.h[r] = f32_to_bf16(vv[r]);
            th[fot][kc] = H.v;
        }

    float* ob = out + (size_t)b * NN * ROWSTRIDE + (size_t)t * 64;
#pragma unroll
    for (int s = 0; s < 2; ++s) {
        uint32_t ed0[4], ed1[4];   // packed agg/(8d): f = 16ft+4q+{0,1}/{2,3}
#pragma unroll
        for (int ft = 0; ft < 4; ++ft) {
            ed0[ft] = pack2(acc[s][ft][0] * inv8d[s], acc[s][ft][1] * inv8d[s]);
            ed1[ft] = pack2(acc[s][ft][2] * inv8d[s], acc[s][ft][3] * inv8d[s]);
        }
        const int n = i0 + s * 16 + l16;
#pragma unroll
        for (int kc = 0; kc < 2; ++kc) {
            bf16x8 bg = shufB(ed0, ed1, kc, srcA, srcB, qhi);
            if (kc == 0) {
#pragma unroll
                for (int fot = 0; fot < 4; ++fot) {
                    f32x4 z = zero4;
                    z = mfma_bf16(th[fot][0], bg, z);
                    acc[s][fot] = z;   // stash partial (acc no longer needed)
                }
            } else {
#pragma unroll
                for (int fot = 0; fot < 4; ++fot) {
                    f32x4 z = mfma_bf16(th[fot][1], bg, acc[s][fot]);
                    float4 o4;
                    o4.x = z[0] > 0.f ? z[0] : 0.f;
                    o4.y = z[1] > 0.f ? z[1] : 0.f;
                    o4.z = z[2] > 0.f ? z[2] : 0.f;
                    o4.w = z[3] > 0.f ? z[3] : 0.f;
                    *(float4*)(ob + (size_t)n * ROWSTRIDE + fot * 16 + q * 4) = o4;
                }
            }
        }
    }
}

extern "C" void kernel_launch(void* const* d_in, const int* in_sizes, int n_in,
                              void* d_out, int out_size, void* d_ws, size_t ws_size,
                              hipStream_t stream) {
    const float* x     = (const float*)d_in[0];   // (8,1024,32,64) fp32
    const float* adj   = (const float*)d_in[1];   // (1024,1024)   fp32
    const float* theta = (const float*)d_in[2];   // (64,64)       fp32
    float* o = (float*)d_out;                     // (8,1024,32,64) fp32

    const size_t adj_bytes = (size_t)NN * NN * sizeof(u16);
    if (ws_size >= adj_bytes) {
        u16* adjb = (u16*)d_ws;
        cvt_adj_kernel<<<dim3(NN * NN / (256 * 4)), dim3(256), 0, stream>>>(adj, adjb);
        attn_gcn_kernel<u16><<<dim3(1024), dim3(512), 0, stream>>>(x, adjb, theta, o);
    } else {
        attn_gcn_kernel<float><<<dim3(1024), dim3(512), 0, stream>>>(x, adj, theta, o);
    }
}

// Round 5
// 292.976 us; speedup vs baseline: 1.4728x; 1.1268x over previous
//
#include <hip/hip_runtime.h>
#include <hip/hip_bf16.h>
#include <cstdint>

// B=8, N=1024, T=32, F=64.  256 independent attention problems of (N=1024, F=64).
// out = relu( ((adj ⊙ softmax(X Xᵀ/8)) X / 8) θᵀ ) per (b,t); X row n = x[b,n,t,:].
// fp32 I/O. Round-10: latency attack on the verified round-9 structure. Counters
// showed latency-bound (MfmaUtil 11 / VALU 29 / HBM 11 / Occ 23): the exposed
// stalls are (1) adj global loads consumed immediately inside the QK inner loop
// and (2) two barriers per K-iter on a single-buffered tile. Fix: (1) adj
// prefetched one full K-tile ahead into registers (issued right after QK consumed
// the previous set -> a whole PV+barrier+stage to cover L2 latency); (2) Xkh/Xv
// double-buffered -> ONE barrier per iter (stage kb+1 writes the idle buffer).
// LDS = 32 KB; shufB P-exchange and all numerics unchanged (absmax 3.9e-3).
#define NN 1024
#define ROWSTRIDE 2048   // NT*NF

typedef __attribute__((ext_vector_type(8))) short bf16x8;
typedef __attribute__((ext_vector_type(4))) float f32x4;
typedef unsigned short u16;

#if __has_builtin(__builtin_amdgcn_exp2f)
#define EXP2(x) __builtin_amdgcn_exp2f(x)
#else
#define EXP2(x) exp2f(x)
#endif

__device__ __forceinline__ f32x4 mfma_bf16(bf16x8 a, bf16x8 b, f32x4 c) {
    return __builtin_amdgcn_mfma_f32_16x16x32_bf16(a, b, c, 0, 0, 0);
}
__device__ __forceinline__ float bf16_to_f32(u16 h) {
    unsigned int u = ((unsigned int)h) << 16;
    return __builtin_bit_cast(float, u);
}
__device__ __forceinline__ u16 f32_to_bf16(float f) {
    __hip_bfloat16 h = __float2bfloat16(f);   // RNE
    return __builtin_bit_cast(u16, h);
}
__device__ __forceinline__ uint32_t pack2(float a, float b) {
    return (uint32_t)f32_to_bf16(a) | ((uint32_t)f32_to_bf16(b) << 16);
}

// adj vector-prefetch traits: one 4-col chunk per (s,kt)
template <typename AT> struct AdjT;
template <> struct AdjT<u16>   { using V = ushort4; };
template <> struct AdjT<float> { using V = float4;  };
__device__ __forceinline__ void cvt4(ushort4 v, float* o) {
    o[0] = bf16_to_f32(v.x); o[1] = bf16_to_f32(v.y);
    o[2] = bf16_to_f32(v.z); o[3] = bf16_to_f32(v.w);
}
__device__ __forceinline__ void cvt4(float4 v, float* o) {
    o[0] = v.x; o[1] = v.y; o[2] = v.z; o[3] = v.w;
}

__global__ void cvt_adj_kernel(const float* __restrict__ a, u16* __restrict__ o) {
    int i = (blockIdx.x * 256 + threadIdx.x) * 4;
    float4 v = *(const float4*)(a + i);
    ushort4 h;
    h.x = f32_to_bf16(v.x); h.y = f32_to_bf16(v.y);
    h.z = f32_to_bf16(v.z); h.w = f32_to_bf16(v.w);
    *(ushort4*)(o + i) = h;
}

// MFMA 16x16x32 layouts (HW-verified):
//   A: A[m=lane&15][k=(lane>>4)*8+r]   B: B[k=(lane>>4)*8+r][n=lane&15]
//   C/D: D[row=(lane>>4)*4+reg][col=lane&15]
//
// C/D -> B-frag transform (keys axis): lane(l16,q') B-frag u32 j of chunk kc comes from
// pk[t=2kc+(q'>>1)] of lane l16+16*(2(q'&1) + (j>>1)), pair d(j&1).
__device__ __forceinline__ bf16x8 shufB(const uint32_t* d0, const uint32_t* d1,
                                        int kc, int srcA, int srcB, bool qhi) {
    uint32_t l0A = (uint32_t)__shfl((int)d0[2*kc],     srcA);
    uint32_t l1A = (uint32_t)__shfl((int)d1[2*kc],     srcA);
    uint32_t l0B = (uint32_t)__shfl((int)d0[2*kc],     srcB);
    uint32_t l1B = (uint32_t)__shfl((int)d1[2*kc],     srcB);
    uint32_t h0A = (uint32_t)__shfl((int)d0[2*kc + 1], srcA);
    uint32_t h1A = (uint32_t)__shfl((int)d1[2*kc + 1], srcA);
    uint32_t h0B = (uint32_t)__shfl((int)d0[2*kc + 1], srcB);
    uint32_t h1B = (uint32_t)__shfl((int)d1[2*kc + 1], srcB);
    union { uint32_t u[4]; bf16x8 v; } R;
    R.u[0] = qhi ? h0A : l0A;
    R.u[1] = qhi ? h1A : l1A;
    R.u[2] = qhi ? h0B : l0B;
    R.u[3] = qhi ? h1B : l1B;
    return R.v;
}

// stage one 64x64 X-tile: row-major Xkh (b128) + transposed Xv (8x b16 scatter)
__device__ __forceinline__ void stage_tile(u16* __restrict__ xk, u16* __restrict__ xv,
                                           float4 g0, float4 g1,
                                           int js, int fcs, int wxf) {
    float vv[8] = {g0.x, g0.y, g0.z, g0.w, g1.x, g1.y, g1.z, g1.w};
    union { u16 h[8]; uint4 u; } H;
#pragma unroll
    for (int r = 0; r < 8; ++r) H.h[r] = f32_to_bf16(vv[r]);
    *(uint4*)&xk[js * 64 + ((fcs ^ (js & 7)) << 3)] = H.u;
#pragma unroll
    for (int r = 0; r < 8; ++r)
        xv[(fcs * 8 + r) * 64 + ((wxf ^ r) << 3) + (js & 7)] = H.h[r];
}

template <typename AT>
__launch_bounds__(512, 2)
__global__ void attn_gcn_kernel(const float* __restrict__ x,
                                const AT*   __restrict__ adj,
                                const float* __restrict__ theta,
                                float* __restrict__ out)
{
    // Xkh: 64 keys x 64 f, 16B-chunk swizzle: phys chunk = fc ^ (key&7)
    // Xv:  64 f x 64 keys (transposed), phys chunk = mc ^ (f&7) ^ (f>>3)
    // Double-buffered: stage(kb+1) writes buf[cur^1] while QK/PV read buf[cur];
    // the single end-of-iter barrier publishes it (prev readers of cur^1 all
    // passed the previous barrier, each wave's own reads drain at barrier entry).
    __shared__ __align__(16) u16 Xkh[2][64 * 64];      // 16384 B
    __shared__ __align__(16) u16 Xv [2][64 * 64];      // 16384 B   (total 32 KB)

    const int tid  = threadIdx.x;
    const int lane = tid & 63;
    const int wid  = tid >> 6;
    const int l16  = lane & 15;
    const int q    = lane >> 4;
    const bool qhi = (q >> 1) != 0;
    const int srcA = l16 + 32 * (q & 1);
    const int srcB = srcA + 16;

    const int blk = blockIdx.x;
    const int p   = blk & 255;        // problem (b*32+t); qb-major for adj L2 reuse
    const int qb  = blk >> 8;
    const int b   = p >> 5;
    const int t   = p & 31;

    const float* xb = x + (size_t)b * NN * ROWSTRIDE + (size_t)t * 64;
    const int    i0 = qb * 256 + wid * 32;   // wave's 32 query rows

    const float SC = 0.125f * 1.44269504088896340736f;   // exp(S/8)=exp2(S*SC)

    // ---- Q B-frags (pre-scaled by SC) + exact row norms (fp32, scaled)
    bf16x8 bq[2][2];
    float  nrm[2] = {0.f, 0.f};
#pragma unroll
    for (int s = 0; s < 2; ++s) {
#pragma unroll
        for (int kc = 0; kc < 2; ++kc) {
            const float* qp = xb + (size_t)(i0 + s * 16 + l16) * ROWSTRIDE + kc * 32 + q * 8;
            float4 v0 = *(const float4*)qp;
            float4 v1 = *(const float4*)(qp + 4);
            float vv[8] = {v0.x, v0.y, v0.z, v0.w, v1.x, v1.y, v1.z, v1.w};
            union { u16 h[8]; bf16x8 v; } H;
#pragma unroll
            for (int r = 0; r < 8; ++r) {
                nrm[s] += vv[r] * vv[r];
                H.h[r] = f32_to_bf16(vv[r] * SC);
            }
            bq[s][kc] = H.v;
        }
        nrm[s] += __shfl_xor(nrm[s], 16);
        nrm[s] += __shfl_xor(nrm[s], 32);
        nrm[s] *= SC;      // diag substitution directly in exp2 domain
    }
    // diagonal location: key n lands in k-tile kbd[s], sub-tile ktd[s],
    // C/D lane q == l16>>2, element r == l16&3   (i0+16s is a multiple of 16)
    const int kbd0 = (i0) >> 6,        ktd0 = ((i0) >> 4) & 3;
    const int kbd1 = (i0 + 16) >> 6,   ktd1 = ((i0 + 16) >> 4) & 3;
    const bool dlane = (q == (l16 >> 2));
    const int  dr    = l16 & 3;

    // per-lane adj row base (n = i0 + 16s + l16), prefetched one K-tile ahead
    const AT* adjr0 = adj + (size_t)(i0 + l16) * NN;
    const AT* adjr1 = adj + (size_t)(i0 + 16 + l16) * NN;
    typename AdjT<AT>::V a_cur[2][4];

    const f32x4 zero4 = {0.f, 0.f, 0.f, 0.f};
    f32x4 acc[2][4];
#pragma unroll
    for (int s = 0; s < 2; ++s)
#pragma unroll
        for (int ft = 0; ft < 4; ++ft) acc[s][ft] = zero4;
    float dp[2] = {0.f, 0.f};

    // staging role: key row js, f-chunk fcs (8 floats)
    const int js = tid >> 3, fcs = tid & 7;
    const int wxf = (js >> 3) ^ fcs;                 // Xv scatter swizzle base
    const float* gbase = xb + (size_t)js * ROWSTRIDE + fcs * 8;

    // ---- prologue: stage kb=0 into buf0; pipeline g (X tile kb+1) + adj (kb=0)
    {
        float4 g0 = *(const float4*)gbase;
        float4 g1 = *(const float4*)(gbase + 4);
        stage_tile(Xkh[0], Xv[0], g0, g1, js, fcs, wxf);
    }
    float4 g0 = *(const float4*)(gbase + (size_t)64 * ROWSTRIDE);
    float4 g1 = *(const float4*)(gbase + (size_t)64 * ROWSTRIDE + 4);
#pragma unroll
    for (int s = 0; s < 2; ++s)
#pragma unroll
        for (int kt = 0; kt < 4; ++kt)
            a_cur[s][kt] = *(const typename AdjT<AT>::V*)
                (((s == 0) ? adjr0 : adjr1) + kt * 16 + q * 4);
    __syncthreads();

#pragma unroll 1
    for (int kb = 0; kb < 16; ++kb) {
        const int cur = kb & 1;
        const u16* xk = Xkh[cur];
        const u16* xv = Xv[cur];

        // ---- Sᵀ = K·Qᵀ (bf16) -> exact-diag fix -> exp -> ×adj -> packed P in regs
        uint32_t pk0[2][4], pk1[2][4];   // [s][kt]: keys 16kt+4q+{0,1} / {2,3}
#pragma unroll
        for (int kt = 0; kt < 4; ++kt) {
            const int base = (kt * 16 + l16) * 64;   // (kt*16+l16)&7 == l16&7
            const int sw   = l16 & 7;
            bf16x8 akh0 = *(const bf16x8*)&xk[base + ((q ^ sw) << 3)];
            bf16x8 akh1 = *(const bf16x8*)&xk[base + (((4 + q) ^ sw) << 3)];
#pragma unroll
            for (int s = 0; s < 2; ++s) {
                f32x4 z = zero4;
                z = mfma_bf16(akh0, bq[s][0], z);
                z = mfma_bf16(akh1, bq[s][1], z);
                // exact diagonal substitution (already in exp2 domain)
                const bool isd = (s == 0) ? (kb == kbd0 && kt == ktd0)
                                          : (kb == kbd1 && kt == ktd1);
                if (isd && dlane) {
#pragma unroll
                    for (int r = 0; r < 4; ++r)
                        if (r == dr) z[r] = nrm[s];
                }
                float av[4];
                cvt4(a_cur[s][kt], av);
                float e0 = EXP2(z[0]), e1 = EXP2(z[1]);
                float e2 = EXP2(z[2]), e3 = EXP2(z[3]);
                dp[s] += (e0 + e1) + (e2 + e3);
                pk0[s][kt] = pack2(e0 * av[0], e1 * av[1]);
                pk1[s][kt] = pack2(e2 * av[2], e3 * av[3]);
            }
        }

        // ---- prefetch adj for kb+1 (a full PV+barrier+stage to cover latency)
        if (kb < 15) {
            const int jn = (kb + 1) * 64;
#pragma unroll
            for (int s = 0; s < 2; ++s)
#pragma unroll
                for (int kt = 0; kt < 4; ++kt)
                    a_cur[s][kt] = *(const typename AdjT<AT>::V*)
                        (((s == 0) ? adjr0 : adjr1) + jn + kt * 16 + q * 4);
        }

        // ---- stage tile kb+1 into the idle buffer (g loaded one iter ago)
        if (kb < 15)
            stage_tile(Xkh[cur ^ 1], Xv[cur ^ 1], g0, g1, js, fcs, wxf);

        // ---- issue global X loads for tile kb+2
        if (kb < 14) {
            const float* gp = gbase + (size_t)(kb + 2) * 64 * ROWSTRIDE;
            g0 = *(const float4*)gp;
            g1 = *(const float4*)(gp + 4);
        }

        // ---- PV: aggᵀ[f][n] += Xv(A) · Pᵀ(B);  Pᵀ B-frags via cross-lane shuffles
#pragma unroll
        for (int kc = 0; kc < 2; ++kc) {
            bf16x8 bp0 = shufB(pk0[0], pk1[0], kc, srcA, srcB, qhi);
            bf16x8 bp1 = shufB(pk0[1], pk1[1], kc, srcA, srcB, qhi);
#pragma unroll
            for (int ft = 0; ft < 4; ++ft) {
                const int fr  = ft * 16 + l16;
                const int swz = (kc * 4 + q) ^ (l16 & 7) ^ ((ft << 1) | (l16 >> 3));
                bf16x8 axv = *(const bf16x8*)&xv[fr * 64 + (swz << 3)];
                acc[0][ft] = mfma_bf16(axv, bp0, acc[0][ft]);
                acc[1][ft] = mfma_bf16(axv, bp1, acc[1][ft]);
            }
        }
        __syncthreads();   // publish stage(kb+1); all buf[cur] reads drained
    }

    // ---- denominator reduce: lanes {l16 + 16q} share n
    float inv8d[2];
#pragma unroll
    for (int s = 0; s < 2; ++s) {
        float v = dp[s];
        v += __shfl_xor(v, 16);
        v += __shfl_xor(v, 32);
        inv8d[s] = 1.0f / (8.0f * v);   // extra 1/sqrt(F) from GCN forward
    }

    // ---- epilogue: outᵀ = θ(A) · aggᵀ(B); agg C/D -> B-frag via shufB (once)
    bf16x8 th[4][2];   // A[m=l16 (fo in tile fot)][k=kc2*32+q*8+r] = θ[fot*16+l16][...]
#pragma unroll
    for (int fot = 0; fot < 4; ++fot)
#pragma unroll
        for (int kc = 0; kc < 2; ++kc) {
            const float* tp = theta + (fot * 16 + l16) * 64 + kc * 32 + q * 8;
            float4 v0 = *(const float4*)tp;
            float4 v1 = *(const float4*)(tp + 4);
            float vv[8] = {v0.x, v0.y, v0.z, v0.w, v1.x, v1.y, v1.z, v1.w};
            union { u16 h[8]; bf16x8 v; } H;
#pragma unroll
            for (int r = 0; r < 8; ++r) H.h[r] = f32_to_bf16(vv[r]);
            th[fot][kc] = H.v;
        }

    float* ob = out + (size_t)b * NN * ROWSTRIDE + (size_t)t * 64;
#pragma unroll
    for (int s = 0; s < 2; ++s) {
        uint32_t ed0[4], ed1[4];   // packed agg/(8d): f = 16ft+4q+{0,1}/{2,3}
#pragma unroll
        for (int ft = 0; ft < 4; ++ft) {
            ed0[ft] = pack2(acc[s][ft][0] * inv8d[s], acc[s][ft][1] * inv8d[s]);
            ed1[ft] = pack2(acc[s][ft][2] * inv8d[s], acc[s][ft][3] * inv8d[s]);
        }
        const int n = i0 + s * 16 + l16;
#pragma unroll
        for (int kc = 0; kc < 2; ++kc) {
            bf16x8 bg = shufB(ed0, ed1, kc, srcA, srcB, qhi);
            if (kc == 0) {
#pragma unroll
                for (int fot = 0; fot < 4; ++fot) {
                    f32x4 z = zero4;
                    z = mfma_bf16(th[fot][0], bg, z);
                    acc[s][fot] = z;   // stash partial (acc no longer needed)
                }
            } else {
#pragma unroll
                for (int fot = 0; fot < 4; ++fot) {
                    f32x4 z = mfma_bf16(th[fot][1], bg, acc[s][fot]);
                    float4 o4;
                    o4.x = z[0] > 0.f ? z[0] : 0.f;
                    o4.y = z[1] > 0.f ? z[1] : 0.f;
                    o4.z = z[2] > 0.f ? z[2] : 0.f;
                    o4.w = z[3] > 0.f ? z[3] : 0.f;
                    *(float4*)(ob + (size_t)n * ROWSTRIDE + fot * 16 + q * 4) = o4;
                }
            }
        }
    }
}

extern "C" void kernel_launch(void* const* d_in, const int* in_sizes, int n_in,
                              void* d_out, int out_size, void* d_ws, size_t ws_size,
                              hipStream_t stream) {
    const float* x     = (const float*)d_in[0];   // (8,1024,32,64) fp32
    const float* adj   = (const float*)d_in[1];   // (1024,1024)   fp32
    const float* theta = (const float*)d_in[2];   // (64,64)       fp32
    float* o = (float*)d_out;                     // (8,1024,32,64) fp32

    const size_t adj_bytes = (size_t)NN * NN * sizeof(u16);
    if (ws_size >= adj_bytes) {
        u16* adjb = (u16*)d_ws;
        cvt_adj_kernel<<<dim3(NN * NN / (256 * 4)), dim3(256), 0, stream>>>(adj, adjb);
        attn_gcn_kernel<u16><<<dim3(1024), dim3(512), 0, stream>>>(x, adjb, theta, o);
    } else {
        attn_gcn_kernel<float><<<dim3(1024), dim3(512), 0, stream>>>(x, adj, theta, o);
    }
}

// Round 6
// 290.809 us; speedup vs baseline: 1.4838x; 1.0074x over previous
//
#include <hip/hip_runtime.h>
#include <hip/hip_bf16.h>
#include <cstdint>

// B=8, N=1024, T=32, F=64.  256 independent attention problems of (N=1024, F=64).
// out = relu( ((adj ⊙ softmax(X Xᵀ/8)) X / 8) θᵀ ) per (b,t); X row n = x[b,n,t,:].
// fp32 I/O. Round-11: kill the P-exchange. Counters showed the per-CU LDS pipe is
// the bottleneck (~444 LDS-cyc/wave-iter, 43% of it the 32 ds_bpermutes of shufB).
// Key layout fact: mfma_f32_16x16x16_bf16's B-frag (B[k=(lane>>4)*4+r][n=lane&15],
// 4 k/lane) EXACTLY matches the C/D layout's 4-rows-per-lane packing -> the QK
// output pk0/pk1 (keys 16kt+4q+{0..3}, query l16, bf16-packed) IS a K=16 B-frag.
// PV and the epilogue both switch to K=16 MFMAs consuming P/agg straight from
// registers: zero cross-lane ops, same MFMA cycles (32xK16 == 16xK32), same LDS
// bytes (16x b64 == 8x b128, swizzle re-derived conflict-free <=2-way).
// Structure otherwise identical to verified round-10 (double-buffered Xkh/Xv, adj
// +1-tile register prefetch, one barrier/iter, builtin exp2, SC folded into Q).
#define NN 1024
#define ROWSTRIDE 2048   // NT*NF

typedef __attribute__((ext_vector_type(8))) short bf16x8;
typedef __attribute__((ext_vector_type(4))) short bf16x4;
typedef __attribute__((ext_vector_type(4))) float f32x4;
typedef unsigned short u16;

#if __has_builtin(__builtin_amdgcn_exp2f)
#define EXP2(x) __builtin_amdgcn_exp2f(x)
#else
#define EXP2(x) exp2f(x)
#endif

__device__ __forceinline__ f32x4 mfma_bf16(bf16x8 a, bf16x8 b, f32x4 c) {
    return __builtin_amdgcn_mfma_f32_16x16x32_bf16(a, b, c, 0, 0, 0);
}

// K=16 bf16 MFMA: builtin name cascade (new-style, gfx90a "_1k", asm fallback).
#if __has_builtin(__builtin_amdgcn_mfma_f32_16x16x16_bf16)
#define MFMA16(a, b, c) __builtin_amdgcn_mfma_f32_16x16x16_bf16(a, b, c, 0, 0, 0)
#elif __has_builtin(__builtin_amdgcn_mfma_f32_16x16x16bf16_1k)
#define MFMA16(a, b, c) __builtin_amdgcn_mfma_f32_16x16x16bf16_1k(a, b, c, 0, 0, 0)
#else
__device__ __forceinline__ f32x4 mfma16_fb(bf16x4 a, bf16x4 b, f32x4 c) {
    f32x4 d;
    // s_nops cover MFMA->VALU read hazard (asm is invisible to the hazard pass)
    asm("v_mfma_f32_16x16x16_bf16 %0, %1, %2, %3\n\ts_nop 7\n\ts_nop 7"
        : "=v"(d) : "v"(a), "v"(b), "v"(c));
    return d;
}
#define MFMA16(a, b, c) mfma16_fb(a, b, c)
#endif

__device__ __forceinline__ float bf16_to_f32(u16 h) {
    unsigned int u = ((unsigned int)h) << 16;
    return __builtin_bit_cast(float, u);
}
__device__ __forceinline__ u16 f32_to_bf16(float f) {
    __hip_bfloat16 h = __float2bfloat16(f);   // RNE
    return __builtin_bit_cast(u16, h);
}
__device__ __forceinline__ uint32_t pack2(float a, float b) {
    return (uint32_t)f32_to_bf16(a) | ((uint32_t)f32_to_bf16(b) << 16);
}

// adj vector-prefetch traits: one 4-col chunk per (s,kt)
template <typename AT> struct AdjT;
template <> struct AdjT<u16>   { using V = ushort4; };
template <> struct AdjT<float> { using V = float4;  };
__device__ __forceinline__ void cvt4(ushort4 v, float* o) {
    o[0] = bf16_to_f32(v.x); o[1] = bf16_to_f32(v.y);
    o[2] = bf16_to_f32(v.z); o[3] = bf16_to_f32(v.w);
}
__device__ __forceinline__ void cvt4(float4 v, float* o) {
    o[0] = v.x; o[1] = v.y; o[2] = v.z; o[3] = v.w;
}

__global__ void cvt_adj_kernel(const float* __restrict__ a, u16* __restrict__ o) {
    int i = (blockIdx.x * 256 + threadIdx.x) * 4;
    float4 v = *(const float4*)(a + i);
    ushort4 h;
    h.x = f32_to_bf16(v.x); h.y = f32_to_bf16(v.y);
    h.z = f32_to_bf16(v.z); h.w = f32_to_bf16(v.w);
    *(ushort4*)(o + i) = h;
}

// MFMA layouts (HW-verified):
//   16x16x32: A[m=lane&15][k=(lane>>4)*8+r]  B[k=(lane>>4)*8+r][n=lane&15]
//   16x16x16: A[m=lane&15][k=(lane>>4)*4+r]  B[k=(lane>>4)*4+r][n=lane&15]
//   C/D (both): D[row=(lane>>4)*4+reg][col=lane&15]
// => C/D of a QK mfma, bf16-packed per 4-row group, is directly a K=16 B-frag.

// stage one 64x64 X-tile: row-major Xkh (b128) + transposed Xv (8x b16 scatter)
__device__ __forceinline__ void stage_tile(u16* __restrict__ xk, u16* __restrict__ xv,
                                           float4 g0, float4 g1,
                                           int js, int fcs, int wxf) {
    float vv[8] = {g0.x, g0.y, g0.z, g0.w, g1.x, g1.y, g1.z, g1.w};
    union { u16 h[8]; uint4 u; } H;
#pragma unroll
    for (int r = 0; r < 8; ++r) H.h[r] = f32_to_bf16(vv[r]);
    *(uint4*)&xk[js * 64 + ((fcs ^ (js & 7)) << 3)] = H.u;
#pragma unroll
    for (int r = 0; r < 8; ++r)
        xv[(fcs * 8 + r) * 64 + ((wxf ^ r) << 3) + (js & 7)] = H.h[r];
}

template <typename AT>
__launch_bounds__(512, 2)
__global__ void attn_gcn_kernel(const float* __restrict__ x,
                                const AT*   __restrict__ adj,
                                const float* __restrict__ theta,
                                float* __restrict__ out)
{
    // Xkh: 64 keys x 64 f, 16B-chunk swizzle: phys chunk = fc ^ (key&7)
    // Xv:  64 f x 64 keys (transposed), phys chunk = (key>>3) ^ (f&7) ^ (f>>3)
    // Double-buffered: stage(kb+1) writes buf[cur^1] while QK/PV read buf[cur].
    __shared__ __align__(16) u16 Xkh[2][64 * 64];      // 16384 B
    __shared__ __align__(16) u16 Xv [2][64 * 64];      // 16384 B   (total 32 KB)

    const int tid  = threadIdx.x;
    const int lane = tid & 63;
    const int wid  = tid >> 6;
    const int l16  = lane & 15;
    const int q    = lane >> 4;

    const int blk = blockIdx.x;
    const int p   = blk & 255;        // problem (b*32+t); qb-major for adj L2 reuse
    const int qb  = blk >> 8;
    const int b   = p >> 5;
    const int t   = p & 31;

    const float* xb = x + (size_t)b * NN * ROWSTRIDE + (size_t)t * 64;
    const int    i0 = qb * 256 + wid * 32;   // wave's 32 query rows

    const float SC = 0.125f * 1.44269504088896340736f;   // exp(S/8)=exp2(S*SC)

    // ---- Q B-frags (pre-scaled by SC) + exact row norms (fp32, scaled)
    bf16x8 bq[2][2];
    float  nrm[2] = {0.f, 0.f};
#pragma unroll
    for (int s = 0; s < 2; ++s) {
#pragma unroll
        for (int kc = 0; kc < 2; ++kc) {
            const float* qp = xb + (size_t)(i0 + s * 16 + l16) * ROWSTRIDE + kc * 32 + q * 8;
            float4 v0 = *(const float4*)qp;
            float4 v1 = *(const float4*)(qp + 4);
            float vv[8] = {v0.x, v0.y, v0.z, v0.w, v1.x, v1.y, v1.z, v1.w};
            union { u16 h[8]; bf16x8 v; } H;
#pragma unroll
            for (int r = 0; r < 8; ++r) {
                nrm[s] += vv[r] * vv[r];
                H.h[r] = f32_to_bf16(vv[r] * SC);
            }
            bq[s][kc] = H.v;
        }
        nrm[s] += __shfl_xor(nrm[s], 16);
        nrm[s] += __shfl_xor(nrm[s], 32);
        nrm[s] *= SC;      // diag substitution directly in exp2 domain
    }
    // diagonal location: key n lands in k-tile kbd[s], sub-tile ktd[s],
    // C/D lane q == l16>>2, element r == l16&3   (i0+16s is a multiple of 16)
    const int kbd0 = (i0) >> 6,        ktd0 = ((i0) >> 4) & 3;
    const int kbd1 = (i0 + 16) >> 6,   ktd1 = ((i0 + 16) >> 4) & 3;
    const bool dlane = (q == (l16 >> 2));
    const int  dr    = l16 & 3;

    // per-lane adj row base (n = i0 + 16s + l16), prefetched one K-tile ahead
    const AT* adjr0 = adj + (size_t)(i0 + l16) * NN;
    const AT* adjr1 = adj + (size_t)(i0 + 16 + l16) * NN;
    typename AdjT<AT>::V a_cur[2][4];

    const f32x4 zero4 = {0.f, 0.f, 0.f, 0.f};
    f32x4 acc[2][4];
#pragma unroll
    for (int s = 0; s < 2; ++s)
#pragma unroll
        for (int ft = 0; ft < 4; ++ft) acc[s][ft] = zero4;
    float dp[2] = {0.f, 0.f};

    // staging role: key row js, f-chunk fcs (8 floats)
    const int js = tid >> 3, fcs = tid & 7;
    const int wxf = (js >> 3) ^ fcs;                 // Xv scatter swizzle base
    const float* gbase = xb + (size_t)js * ROWSTRIDE + fcs * 8;

    // ---- prologue: stage kb=0 into buf0; pipeline g (X tile kb+1) + adj (kb=0)
    {
        float4 g0p = *(const float4*)gbase;
        float4 g1p = *(const float4*)(gbase + 4);
        stage_tile(Xkh[0], Xv[0], g0p, g1p, js, fcs, wxf);
    }
    float4 g0 = *(const float4*)(gbase + (size_t)64 * ROWSTRIDE);
    float4 g1 = *(const float4*)(gbase + (size_t)64 * ROWSTRIDE + 4);
#pragma unroll
    for (int s = 0; s < 2; ++s)
#pragma unroll
        for (int kt = 0; kt < 4; ++kt)
            a_cur[s][kt] = *(const typename AdjT<AT>::V*)
                (((s == 0) ? adjr0 : adjr1) + kt * 16 + q * 4);
    __syncthreads();

#pragma unroll 1
    for (int kb = 0; kb < 16; ++kb) {
        const int cur = kb & 1;
        const u16* xk = Xkh[cur];
        const u16* xv = Xv[cur];

        // ---- Sᵀ = K·Qᵀ (bf16) -> exact-diag fix -> exp -> ×adj -> packed P in regs
        uint32_t pk0[2][4], pk1[2][4];   // [s][kt]: keys 16kt+4q+{0,1} / {2,3}
#pragma unroll
        for (int kt = 0; kt < 4; ++kt) {
            const int base = (kt * 16 + l16) * 64;   // (kt*16+l16)&7 == l16&7
            const int sw   = l16 & 7;
            bf16x8 akh0 = *(const bf16x8*)&xk[base + ((q ^ sw) << 3)];
            bf16x8 akh1 = *(const bf16x8*)&xk[base + (((4 + q) ^ sw) << 3)];
#pragma unroll
            for (int s = 0; s < 2; ++s) {
                f32x4 z = zero4;
                z = mfma_bf16(akh0, bq[s][0], z);
                z = mfma_bf16(akh1, bq[s][1], z);
                // exact diagonal substitution (already in exp2 domain)
                const bool isd = (s == 0) ? (kb == kbd0 && kt == ktd0)
                                          : (kb == kbd1 && kt == ktd1);
                if (isd && dlane) {
#pragma unroll
                    for (int r = 0; r < 4; ++r)
                        if (r == dr) z[r] = nrm[s];
                }
                float av[4];
                cvt4(a_cur[s][kt], av);
                float e0 = EXP2(z[0]), e1 = EXP2(z[1]);
                float e2 = EXP2(z[2]), e3 = EXP2(z[3]);
                dp[s] += (e0 + e1) + (e2 + e3);
                pk0[s][kt] = pack2(e0 * av[0], e1 * av[1]);
                pk1[s][kt] = pack2(e2 * av[2], e3 * av[3]);
            }
        }

        // ---- prefetch adj for kb+1 (a full PV+barrier+stage to cover latency)
        if (kb < 15) {
            const int jn = (kb + 1) * 64;
#pragma unroll
            for (int s = 0; s < 2; ++s)
#pragma unroll
                for (int kt = 0; kt < 4; ++kt)
                    a_cur[s][kt] = *(const typename AdjT<AT>::V*)
                        (((s == 0) ? adjr0 : adjr1) + jn + kt * 16 + q * 4);
        }

        // ---- stage tile kb+1 into the idle buffer (g loaded one iter ago)
        if (kb < 15)
            stage_tile(Xkh[cur ^ 1], Xv[cur ^ 1], g0, g1, js, fcs, wxf);

        // ---- issue global X loads for tile kb+2
        if (kb < 14) {
            const float* gp = gbase + (size_t)(kb + 2) * 64 * ROWSTRIDE;
            g0 = *(const float4*)gp;
            g1 = *(const float4*)(gp + 4);
        }

        // ---- PV (K=16): aggᵀ[f][n] += Xv(A) · P(B); B = pk pairs, no exchange.
        //      A[m=f-sub l16][k=key 4q+r]: keys 16kt+4q+{0..3} from Xv chunk
        //      mc=2kt+(q>>1), half (q&1)*4; phys chunk = mc ^ (f&7) ^ (f>>3).
#pragma unroll
        for (int kt = 0; kt < 4; ++kt) {
            union { uint32_t u[2]; bf16x4 v; } B0, B1;
            B0.u[0] = pk0[0][kt]; B0.u[1] = pk1[0][kt];
            B1.u[0] = pk0[1][kt]; B1.u[1] = pk1[1][kt];
            const int mc = (kt << 1) | (q >> 1);
#pragma unroll
            for (int ft = 0; ft < 4; ++ft) {
                const int f     = ft * 16 + l16;
                const int chunk = mc ^ (l16 & 7) ^ ((ft << 1) | (l16 >> 3));
                const bf16x4 a  = *(const bf16x4*)
                    &xv[f * 64 + (chunk << 3) + ((q & 1) << 2)];
                acc[0][ft] = MFMA16(a, B0.v, acc[0][ft]);
                acc[1][ft] = MFMA16(a, B1.v, acc[1][ft]);
            }
        }
        __syncthreads();   // publish stage(kb+1); all buf[cur] reads drained
    }

    // ---- denominator reduce: lanes {l16 + 16q} share n
    float inv8d[2];
#pragma unroll
    for (int s = 0; s < 2; ++s) {
        float v = dp[s];
        v += __shfl_xor(v, 16);
        v += __shfl_xor(v, 32);
        inv8d[s] = 1.0f / (8.0f * v);   // extra 1/sqrt(F) from GCN forward
    }

    // ---- epilogue (K=16): outᵀ = θ(A) · aggᵀ(B); agg C/D IS the B-frag.
    //      A[m=fo l16][k=f' 4q+r] = θ[fot*16+l16][ktf*16+4q+r]
    bf16x4 th4[4][4];
#pragma unroll
    for (int fot = 0; fot < 4; ++fot)
#pragma unroll
        for (int ktf = 0; ktf < 4; ++ktf) {
            const float* tp = theta + (fot * 16 + l16) * 64 + ktf * 16 + q * 4;
            float4 v = *(const float4*)tp;
            union { u16 h[4]; bf16x4 b; } H;
            H.h[0] = f32_to_bf16(v.x); H.h[1] = f32_to_bf16(v.y);
            H.h[2] = f32_to_bf16(v.z); H.h[3] = f32_to_bf16(v.w);
            th4[fot][ktf] = H.b;
        }

    float* ob = out + (size_t)b * NN * ROWSTRIDE + (size_t)t * 64;
#pragma unroll
    for (int s = 0; s < 2; ++s) {
        bf16x4 bg[4];
#pragma unroll
        for (int ktf = 0; ktf < 4; ++ktf) {
            union { uint32_t u[2]; bf16x4 v; } G;
            G.u[0] = pack2(acc[s][ktf][0] * inv8d[s], acc[s][ktf][1] * inv8d[s]);
            G.u[1] = pack2(acc[s][ktf][2] * inv8d[s], acc[s][ktf][3] * inv8d[s]);
            bg[ktf] = G.v;
        }
        const int n = i0 + s * 16 + l16;
#pragma unroll
        for (int fot = 0; fot < 4; ++fot) {
            f32x4 z = zero4;
#pragma unroll
            for (int ktf = 0; ktf < 4; ++ktf)
                z = MFMA16(th4[fot][ktf], bg[ktf], z);
            float4 o4;
            o4.x = z[0] > 0.f ? z[0] : 0.f;
            o4.y = z[1] > 0.f ? z[1] : 0.f;
            o4.z = z[2] > 0.f ? z[2] : 0.f;
            o4.w = z[3] > 0.f ? z[3] : 0.f;
            *(float4*)(ob + (size_t)n * ROWSTRIDE + fot * 16 + q * 4) = o4;
        }
    }
}

extern "C" void kernel_launch(void* const* d_in, const int* in_sizes, int n_in,
                              void* d_out, int out_size, void* d_ws, size_t ws_size,
                              hipStream_t stream) {
    const float* x     = (const float*)d_in[0];   // (8,1024,32,64) fp32
    const float* adj   = (const float*)d_in[1];   // (1024,1024)   fp32
    const float* theta = (const float*)d_in[2];   // (64,64)       fp32
    float* o = (float*)d_out;                     // (8,1024,32,64) fp32

    const size_t adj_bytes = (size_t)NN * NN * sizeof(u16);
    if (ws_size >= adj_bytes) {
        u16* adjb = (u16*)d_ws;
        cvt_adj_kernel<<<dim3(NN * NN / (256 * 4)), dim3(256), 0, stream>>>(adj, adjb);
        attn_gcn_kernel<u16><<<dim3(1024), dim3(512), 0, stream>>>(x, adjb, theta, o);
    } else {
        attn_gcn_kernel<float><<<dim3(1024), dim3(512), 0, stream>>>(x, adj, theta, o);
    }
}